// Round 12
// baseline (176.886 us; speedup 1.0000x reference)
//
#include <hip/hip_runtime.h>
#include <cmath>

namespace {
constexpr int NB  = 256;   // batch
constexpr int CI  = 64;    // in channels
constexpr int CO  = 64;    // out channels
constexpr int TT  = 64;    // time
constexpr int V   = 25;    // vertices
constexpr int REL = 8;     // rel channels
constexpr int TV  = TT * V;   // 1600
constexpr int CC  = 8;     // channels per fused block
constexpr int IP  = 28;    // inp row pad (16B-aligned rows)
constexpr int AP  = 28;    // Af row pad (16B-aligned rows)
}

typedef float f4 __attribute__((ext_vector_type(4)));

__device__ __forceinline__ float fast_tanh(float x) {
  float ax = fabsf(x);
  float e  = __expf(-2.f * ax);          // v_exp based
  float r  = (1.f - e) / (1.f + e);
  return copysignf(r, x);
}

// ---------------------------------------------------------------------------
// K1: per-n temporal reduction -> x1,x2 (REL*V each) into ws. (unchanged)
// ---------------------------------------------------------------------------
__global__ __launch_bounds__(1024) void k1_x12(
    const float* __restrict__ x,
    const float* __restrict__ w1, const float* __restrict__ b1,
    const float* __restrict__ w2, const float* __restrict__ b2,
    float* __restrict__ ws) {
  const int n = blockIdx.x;
  const int tid = threadIdx.x;
  __shared__ __align__(16) float xs[8][TV];
  __shared__ float xsum[CI][V];
  __shared__ float w12[2][REL][CI];

  for (int idx = tid; idx < 2 * REL * CI; idx += 1024) {
    int half = idx / (REL * CI), rem = idx % (REL * CI);
    w12[half][rem / CI][rem % CI] = half ? w2[rem] : w1[rem];
  }

  const float4* xb = reinterpret_cast<const float4*>(x + (size_t)n * (CI * TV));
  float4* xsv = reinterpret_cast<float4*>(&xs[0][0]);
  constexpr int V4G = 8 * TV / 4;  // 3200

  for (int g = 0; g < 8; ++g) {
    __syncthreads();
    for (int idx = tid; idx < V4G; idx += 1024)
      xsv[idx] = xb[g * V4G + idx];
    __syncthreads();
    if (tid < 8 * V) {
      int ch = tid / V, v = tid % V;
      float acc = 0.f;
      #pragma unroll
      for (int t = 0; t < TT; ++t) acc += xs[ch][t * V + v];
      xsum[g * 8 + ch][v] = acc;
    }
  }
  __syncthreads();

  if (tid < 2 * REL * V) {
    int half = tid / (REL * V), rem = tid % (REL * V);
    int r = rem / V, v = rem % V;
    float a = 0.f;
    #pragma unroll
    for (int i = 0; i < CI; ++i) a = fmaf(w12[half][r][i], xsum[i][v], a);
    ws[(size_t)n * (2 * REL * V) + tid] = a * (1.f / TT) + (half ? b2[r] : b1[r]);
  }
}

// ---------------------------------------------------------------------------
// K2 fused (R11 frame). Round-12 changes:
//  - P2: 8 t-rows/thread on 256 threads -> per chk 15 LDS reads / 224 FMA
//    (block DS 7.4K -> 5.0K cyc); Af-row reads amortized over 8 t-rows.
//  - P1: #pragma unroll 8 (8 float4 loads in flight).
//  - fast_tanh (v_exp) instead of libm tanhf.
//  - zero only the 3 pad floats per inp row.
// LDS 79744 B -> 2 blocks/CU. wr/br/w3/b3 via wave-uniform s_loads.
// ---------------------------------------------------------------------------
__global__ __launch_bounds__(512, 4) void k2_fused(
    const float* __restrict__ x, const float* __restrict__ A,
    const float* __restrict__ w3, const float* __restrict__ b3,
    const float* __restrict__ wr, const float* __restrict__ br,
    const float* __restrict__ ws, float* __restrict__ out) {
  const int id  = blockIdx.x;
  const int n   = (id & 7) | ((id >> 3) & ~7);
  const int cb  = (id >> 3) & 7;
  const int c0  = cb * CC;
  const int tid = threadIdx.x;       // 0..511

  __shared__ __align__(16) float inp[CC * TT * IP];   // 57344 B
  __shared__ __align__(16) float Afs[CC * V * AP];    // 22400 B

  // ---- P0a: zero inp pad columns (v=25..27) for all 512 rows
  {
    float* row = inp + tid * IP;     // tid == row index (8cc*64t = 512)
    row[25] = 0.f; row[26] = 0.f; row[27] = 0.f;
  }

  // ---- P0b: Af[cc][u][v] = A[u][v]+b3[c]+sum_r w3[c][r]*tanh(x1[r][u]-x2[r][v])
  //           pad columns (v>=25) = 0 (so f4 chunk 6 is safe)
  const float* x1n = ws + (size_t)n * (2 * REL * V);
  const float* x2n = x1n + REL * V;
  for (int idx = tid; idx < V * AP; idx += 512) {      // 700 tasks
    int u = idx / AP, v = idx % AP;
    if (v < V) {
      float t8[REL];
      #pragma unroll
      for (int r = 0; r < REL; ++r)
        t8[r] = fast_tanh(x1n[r * V + u] - x2n[r * V + v]);
      const float base = A[u * V + v];
      #pragma unroll
      for (int cc = 0; cc < CC; ++cc) {
        float acc = base + b3[c0 + cc];                // uniform -> s_load
        #pragma unroll
        for (int r = 0; r < REL; ++r)
          acc = fmaf(w3[(c0 + cc) * REL + r], t8[r], acc);  // uniform -> s_load
        Afs[(cc * V + u) * AP + v] = acc;
      }
    } else {
      #pragma unroll
      for (int cc = 0; cc < CC; ++cc)
        Afs[(cc * V + u) * AP + v] = 0.f;
    }
  }
  __syncthreads();

  // ---- P1: inputs tile (all t) into LDS. 400 threads own float4 tv-columns.
  //          weights via uniform global reads -> s_load.
  if (tid < TV / 4) {
    const float* xp = x + (size_t)n * (CI * TV) + tid * 4;
    float acc[CC][4];
    #pragma unroll
    for (int cc = 0; cc < CC; ++cc) {
      float b = br[c0 + cc];                           // uniform -> s_load
      acc[cc][0] = b; acc[cc][1] = b; acc[cc][2] = b; acc[cc][3] = b;
    }
    #pragma unroll 8
    for (int i = 0; i < CI; ++i) {
      float4 xv = *reinterpret_cast<const float4*>(xp + (size_t)i * TV);
      float w8[CC];
      #pragma unroll
      for (int cc = 0; cc < CC; ++cc)
        w8[cc] = wr[(size_t)(c0 + cc) * CI + i];       // uniform -> s_load
      #pragma unroll
      for (int cc = 0; cc < CC; ++cc) {
        acc[cc][0] = fmaf(w8[cc], xv.x, acc[cc][0]);
        acc[cc][1] = fmaf(w8[cc], xv.y, acc[cc][1]);
        acc[cc][2] = fmaf(w8[cc], xv.z, acc[cc][2]);
        acc[cc][3] = fmaf(w8[cc], xv.w, acc[cc][3]);
      }
    }
    int tv0 = tid * 4;
    int t = tv0 / V, v = tv0 % V;
    #pragma unroll
    for (int k = 0; k < 4; ++k) {
      #pragma unroll
      for (int cc = 0; cc < CC; ++cc)
        inp[(cc * TT + t) * IP + v] = acc[cc][k];
      if (++v == V) { v = 0; ++t; }
    }
  }
  __syncthreads();

  // ---- P2 (tid < 256): thread = (cc, tq, uq). t-rows {tq + 8*ti, ti=0..7};
  //      u-rows {6*uq .. 6*uq+6} (overlap at 6/12/18 -> benign dup stores).
  //      Per chk: 8 inp f4 + 7 Af f4 reads, 224 FMA. All indices compile-time.
  if (tid < 256) {
    const int cc = tid >> 5;          // 0..7
    const int tq = (tid >> 2) & 7;    // 0..7
    const int uq = tid & 3;           // 0..3
    const int u0 = uq * 6;

    float acc[8][7];
    #pragma unroll
    for (int a = 0; a < 8; ++a)
      #pragma unroll
      for (int b = 0; b < 7; ++b) acc[a][b] = 0.f;

    const float* ib = &inp[(cc * TT + tq) * IP];
    const float* ab = &Afs[(cc * V + u0) * AP];

    #pragma unroll
    for (int chk = 0; chk < 7; ++chk) {
      f4 xr[8];
      #pragma unroll
      for (int ti = 0; ti < 8; ++ti)
        xr[ti] = *reinterpret_cast<const f4*>(ib + ti * 8 * IP + chk * 4);
      #pragma unroll
      for (int ku = 0; ku < 7; ++ku) {
        const f4 a = *reinterpret_cast<const f4*>(ab + ku * AP + chk * 4);
        #pragma unroll
        for (int ti = 0; ti < 8; ++ti)
          acc[ti][ku] = fmaf(a.w, xr[ti].w,
                        fmaf(a.z, xr[ti].z,
                        fmaf(a.y, xr[ti].y,
                        fmaf(a.x, xr[ti].x, acc[ti][ku]))));
      }
    }

    float* ob = out + ((size_t)n * CO + (c0 + cc)) * (size_t)(TT * V);
    #pragma unroll
    for (int ti = 0; ti < 8; ++ti) {
      const int t = tq + 8 * ti;
      #pragma unroll
      for (int ku = 0; ku < 7; ++ku)
        ob[t * V + u0 + ku] = acc[ti][ku];
    }
  }
}

extern "C" void kernel_launch(void* const* d_in, const int* in_sizes, int n_in,
                              void* d_out, int out_size, void* d_ws, size_t ws_size,
                              hipStream_t stream) {
  (void)in_sizes; (void)n_in; (void)out_size; (void)ws_size;
  const float* x  = (const float*)d_in[0];
  const float* A  = (const float*)d_in[1];
  const float* w1 = (const float*)d_in[2];
  const float* b1 = (const float*)d_in[3];
  const float* w2 = (const float*)d_in[4];
  const float* b2 = (const float*)d_in[5];
  const float* w3 = (const float*)d_in[6];
  const float* b3 = (const float*)d_in[7];
  const float* wr = (const float*)d_in[8];
  const float* br = (const float*)d_in[9];
  float* out = (float*)d_out;
  float* ws  = (float*)d_ws;

  hipLaunchKernelGGL(k1_x12, dim3(NB), dim3(1024), 0, stream,
                     x, w1, b1, w2, b2, ws);
  hipLaunchKernelGGL(k2_fused, dim3(NB * CO / CC), dim3(512), 0, stream,
                     x, A, w3, b3, wr, br, ws, out);
}